// Round 6
// baseline (178.474 us; speedup 1.0000x reference)
//
#include <hip/hip_runtime.h>

typedef __bf16 bf16;
typedef unsigned int u32;
typedef __attribute__((ext_vector_type(8))) __bf16 bf16x8;
typedef __attribute__((ext_vector_type(4))) __bf16 bf16x4;
typedef __attribute__((ext_vector_type(4))) float floatx4;

#define IN_DIM  768
#define ATT_DIM 512
#define NH      8
#define HD      64
#define BATCH   4
#define SEQ     2048
#define M_TOT   (BATCH*SEQ)     // 8192
#define QKV_N   (3*ATT_DIM)     // 1536

// Q scale: 1/sqrt(64) * log2(e)  -> scores exit MFMA in log2 domain
#define QSCALE 0.18033688011112042f

// async 16B global->LDS copy. LDS dest = wave-uniform base + lane*16.
__device__ __forceinline__ void cp16(void* lds, const void* g) {
    __builtin_amdgcn_global_load_lds((const __attribute__((address_space(1))) u32*)g,
                                     (__attribute__((address_space(3))) u32*)lds, 16, 0, 0);
}
// XOR-swizzled accessor for 64-col bf16 tiles staged by cp16:
// 16B chunk c of row r lives at slot c ^ (r&7).  (R2-measured: ~free)
__device__ __forceinline__ const bf16* swz(const bf16* b, int row, int chunk) {
    return b + row * 64 + (((chunk) ^ (row & 7)) << 3);
}

// ---------------------------------------------------------------------------
// Kernel 0: fp32 -> bf16 conversion of X, W_qkv, W_out
// ---------------------------------------------------------------------------
#define N8_X  (M_TOT * IN_DIM / 8)
#define N8_WQ (QKV_N * IN_DIM / 8)
#define N8_WO (IN_DIM * ATT_DIM / 8)
#define N8_ALL (N8_X + N8_WQ + N8_WO)

__global__ __launch_bounds__(256) void cvt_all(const float* __restrict__ X,
                                               const float* __restrict__ Wq,
                                               const float* __restrict__ Wo,
                                               bf16* __restrict__ Xb,
                                               bf16* __restrict__ Wqb,
                                               bf16* __restrict__ Wob) {
    int i = blockIdx.x * 256 + threadIdx.x;
    const float* s; bf16* d; int off;
    if (i < N8_X)            { s = X;  d = Xb;  off = i; }
    else if (i < N8_X+N8_WQ) { s = Wq; d = Wqb; off = i - N8_X; }
    else                     { s = Wo; d = Wob; off = i - N8_X - N8_WQ; }
    const float4 a = ((const float4*)s)[2*off];
    const float4 b = ((const float4*)s)[2*off+1];
    bf16x8 o = {(bf16)a.x,(bf16)a.y,(bf16)a.z,(bf16)a.w,
                (bf16)b.x,(bf16)b.y,(bf16)b.z,(bf16)b.w};
    ((bf16x8*)d)[off] = o;
}

// ---------------------------------------------------------------------------
// Kernel 1: QKV = Xb * Wqkvb^T (bf16, DMA-staged, BK=64).
// Q,K -> [b][h][n][d] (Q pre-scaled); V -> transposed [b][h][d][n] via LDS.
// ---------------------------------------------------------------------------
__global__ __launch_bounds__(256) void qkv_gemm(const bf16* __restrict__ Xb,
                                                const bf16* __restrict__ Wb,
                                                bf16* __restrict__ Q,
                                                bf16* __restrict__ Kv,
                                                bf16* __restrict__ VT) {
    __shared__ __align__(16) char smraw[34816];
    bf16* As = (bf16*)smraw;
    bf16* Bs = (bf16*)(smraw + 16384);

    const int tid  = threadIdx.x;
    const int bm0  = blockIdx.y * 128;
    const int bn0  = blockIdx.x * 128;
    const int wave = tid >> 6, lane = tid & 63;
    const int quad = lane >> 4, l15 = lane & 15;
    const int wm = (wave >> 1) * 64, wn = (wave & 1) * 64;
    const int r8 = lane >> 3, cc = (lane & 7) ^ r8;

    const bf16* ag = Xb + (size_t)(bm0 + wave * 32 + r8) * IN_DIM + cc * 8;
    const bf16* bg = Wb + (size_t)(bn0 + wave * 32 + r8) * IN_DIM + cc * 8;

    floatx4 acc[4][4];
#pragma unroll
    for (int i = 0; i < 4; ++i)
#pragma unroll
        for (int j = 0; j < 4; ++j) acc[i][j] = (floatx4){0.f, 0.f, 0.f, 0.f};

    for (int kt = 0; kt < IN_DIM / 64; ++kt) {
        __syncthreads();
#pragma unroll
        for (int it = 0; it < 4; ++it) {
            cp16(&As[(wave * 32 + it * 8) * 64], ag + it * (8 * IN_DIM) + kt * 64);
            cp16(&Bs[(wave * 32 + it * 8) * 64], bg + it * (8 * IN_DIM) + kt * 64);
        }
        __syncthreads();

        bf16x8 af[2][4], bfr[2][4];
#pragma unroll
        for (int kh = 0; kh < 2; ++kh)
#pragma unroll
            for (int i = 0; i < 4; ++i) {
                af[kh][i]  = *(const bf16x8*)swz(As, wm + i * 16 + l15, kh * 4 + quad);
                bfr[kh][i] = *(const bf16x8*)swz(Bs, wn + i * 16 + l15, kh * 4 + quad);
            }
#pragma unroll
        for (int kh = 0; kh < 2; ++kh)
#pragma unroll
            for (int i = 0; i < 4; ++i)
#pragma unroll
                for (int j = 0; j < 4; ++j)
                    acc[i][j] = __builtin_amdgcn_mfma_f32_16x16x32_bf16(af[kh][i], bfr[kh][j], acc[i][j], 0, 0, 0);
    }

    const int b = bm0 >> 11, nbase = bm0 & 2047;

    if (bn0 < 1024) {
#pragma unroll
        for (int i = 0; i < 4; ++i)
#pragma unroll
            for (int j = 0; j < 4; ++j)
#pragma unroll
                for (int r = 0; r < 4; ++r) {
                    const int row = bm0 + wm + i * 16 + quad * 4 + r;
                    const int col = bn0 + wn + j * 16 + l15;
                    const float v = acc[i][j][r];
                    const int rem = col & 511;
                    const int h = rem >> 6, d = rem & 63;
                    const int n = row & 2047;
                    const size_t idx = (((size_t)((row >> 11) * NH + h)) * SEQ + n) * HD + d;
                    if (col < 512) Q[idx]  = (bf16)(v * QSCALE);
                    else           Kv[idx] = (bf16)v;
                }
    } else {
        __syncthreads();
        bf16 (*Ts)[136] = (bf16(*)[136])smraw;
#pragma unroll
        for (int i = 0; i < 4; ++i)
#pragma unroll
            for (int j = 0; j < 4; ++j) {
                bf16x4 pk = {(bf16)acc[i][j][0], (bf16)acc[i][j][1],
                             (bf16)acc[i][j][2], (bf16)acc[i][j][3]};
                *(bf16x4*)&Ts[wn + j * 16 + l15][wm + i * 16 + quad * 4] = pk;
            }
        __syncthreads();
        const int cb = bn0 - 1024;
#pragma unroll
        for (int t2 = 0; t2 < 8; ++t2) {
            const int id = tid + t2 * 256;
            const int c = id >> 4, nc = (id & 15) * 8;
            const int col = cb + c;
            const int h = col >> 6, d = col & 63;
            *(bf16x8*)&VT[(((size_t)(b * NH + h)) * HD + d) * SEQ + nbase + nc] =
                *(const bf16x8*)&Ts[c][nc];
        }
    }
}

// ---------------------------------------------------------------------------
// Kernel 2: flash attention, no-max softmax, S^T scheme, 32 q-rows/wave.
// Block = 128 Q rows (4 waves x 2 groups x 16 rows), grid (32 bh, 16 qt) =
// 512 blocks, 2/CU. K/V dbuf, ONE barrier/iter (DMA has a full iter in
// flight). K/V LDS reads shared across both q-groups -> ~9 LDS cy per MFMA
// (was 15). Per-wave P strips (one per group), chunk-swizzled.
// ---------------------------------------------------------------------------
__global__ __launch_bounds__(256, 2) void attn(const bf16* __restrict__ Q,
                                               const bf16* __restrict__ K,
                                               const bf16* __restrict__ VT,
                                               bf16* __restrict__ Y) {
    __shared__ bf16 Ks[2][64 * 64];     // 16 KB, swizzled
    __shared__ bf16 VTs[2][64 * 64];    // 16 KB, swizzled [d][key]
    __shared__ bf16 Ps[4][2][16 * 64];  // 16 KB, per-wave per-group strips

    const int tid  = threadIdx.x;
    const int wave = tid >> 6, lane = tid & 63;
    const int quad = lane >> 4, l15 = lane & 15;
    const int bh = blockIdx.x;                 // bh fast dim: same-XCD L2 reuse
    const int q0 = blockIdx.y * 128;
    const bf16* Qg = Q  + (size_t)bh * SEQ * HD;
    const bf16* Kg = K  + (size_t)bh * SEQ * HD;
    const bf16* Vg = VT + (size_t)bh * HD * SEQ;

    const int r8 = lane >> 3, cc = (lane & 7) ^ r8;

    // Q fragments straight from global (once): 2 groups x 16 rows
    bf16x8 aq[2][2];
#pragma unroll
    for (int g = 0; g < 2; ++g) {
        const size_t qrow = (size_t)(q0 + wave * 32 + g * 16 + l15) * 64;
        aq[g][0] = *(const bf16x8*)&Qg[qrow + quad * 8];
        aq[g][1] = *(const bf16x8*)&Qg[qrow + 32 + quad * 8];
    }

    const bf16* kg0 = Kg + (size_t)(wave * 16 + r8) * 64 + cc * 8;
    const bf16* kg1 = Kg + (size_t)(wave * 16 + 8 + r8) * 64 + cc * 8;
    const bf16* vg0 = Vg + (size_t)(wave * 16 + r8) * 2048 + cc * 8;
    const bf16* vg1 = Vg + (size_t)(wave * 16 + 8 + r8) * 2048 + cc * 8;

    // prologue: K(0), V(0) into buf 0
    cp16(&Ks[0][(wave * 16) * 64], kg0);
    cp16(&Ks[0][(wave * 16 + 8) * 64], kg1);
    cp16(&VTs[0][(wave * 16) * 64], vg0);
    cp16(&VTs[0][(wave * 16 + 8) * 64], vg1);

    float l[2] = {0.f, 0.f};
    floatx4 o[2][4];
#pragma unroll
    for (int g = 0; g < 2; ++g)
#pragma unroll
        for (int db = 0; db < 4; ++db) o[g][db] = (floatx4){0.f, 0.f, 0.f, 0.f};

    for (int kt = 0; kt < SEQ / 64; ++kt) {
        const int cur = kt & 1, nb = cur ^ 1;
        // drains DMA(kt) (issued one full iteration ago) + frees buf[nb]
        __syncthreads();
        if (kt < SEQ / 64 - 1) {
            cp16(&Ks[nb][(wave * 16) * 64], kg0 + (size_t)(kt + 1) * 4096);
            cp16(&Ks[nb][(wave * 16 + 8) * 64], kg1 + (size_t)(kt + 1) * 4096);
            cp16(&VTs[nb][(wave * 16) * 64], vg0 + (kt + 1) * 64);
            cp16(&VTs[nb][(wave * 16 + 8) * 64], vg1 + (kt + 1) * 64);
        }

        // S^T phase: K frags shared across both q-groups.
        // Lane holds P[q=l15][key=t*16+quad*4+r] for group g.
#pragma unroll
        for (int t = 0; t < 4; ++t) {
            const int kr = t * 16 + l15;
            const bf16x8 k0 = *(const bf16x8*)swz(Ks[cur], kr, quad);
            const bf16x8 k1 = *(const bf16x8*)swz(Ks[cur], kr, 4 + quad);
            const int c = t * 2 + (quad >> 1);
            const int poff = l15 * 64 + ((c ^ (l15 & 7)) << 3) + ((quad & 1) << 2);
#pragma unroll
            for (int g = 0; g < 2; ++g) {
                floatx4 z = (floatx4){0.f, 0.f, 0.f, 0.f};
                z = __builtin_amdgcn_mfma_f32_16x16x32_bf16(k0, aq[g][0], z, 0, 0, 0);
                z = __builtin_amdgcn_mfma_f32_16x16x32_bf16(k1, aq[g][1], z, 0, 0, 0);
                const float p0 = __builtin_amdgcn_exp2f(z[0]);
                const float p1 = __builtin_amdgcn_exp2f(z[1]);
                const float p2 = __builtin_amdgcn_exp2f(z[2]);
                const float p3 = __builtin_amdgcn_exp2f(z[3]);
                l[g] += (p0 + p1) + (p2 + p3);
                bf16x4 pk = {(bf16)p0, (bf16)p1, (bf16)p2, (bf16)p3};
                *(bf16x4*)&Ps[wave][g][poff] = pk;
            }
        }
        // P A-fragments (contiguous in key, read through the same swizzle)
        bf16x8 pa[2][2];
#pragma unroll
        for (int g = 0; g < 2; ++g) {
            pa[g][0] = *(const bf16x8*)swz(&Ps[wave][g][0], l15, quad);
            pa[g][1] = *(const bf16x8*)swz(&Ps[wave][g][0], l15, 4 + quad);
        }

        // O += P*V ; V frags shared across both q-groups
#pragma unroll
        for (int db = 0; db < 4; ++db) {
            const int vr = db * 16 + l15;
            const bf16x8 v0 = *(const bf16x8*)swz(VTs[cur], vr, quad);
            const bf16x8 v1 = *(const bf16x8*)swz(VTs[cur], vr, 4 + quad);
#pragma unroll
            for (int g = 0; g < 2; ++g) {
                o[g][db] = __builtin_amdgcn_mfma_f32_16x16x32_bf16(pa[g][0], v0, o[g][db], 0, 0, 0);
                o[g][db] = __builtin_amdgcn_mfma_f32_16x16x32_bf16(pa[g][1], v1, o[g][db], 0, 0, 0);
            }
        }
    }

    // final row-sum reduction + distribute 1/l to C-layout rows, write
    const int b = bh >> 3, h = bh & 7;
#pragma unroll
    for (int g = 0; g < 2; ++g) {
        float lg = l[g];
        lg += __shfl_xor(lg, 16, 64);
        lg += __shfl_xor(lg, 32, 64);
        const float inv = 1.0f / lg;
        float linv[4];
#pragma unroll
        for (int r = 0; r < 4; ++r)
            linv[r] = __int_as_float(__builtin_amdgcn_ds_bpermute((quad * 4 + r) * 4,
                                                                  __float_as_int(inv)));
#pragma unroll
        for (int db = 0; db < 4; ++db)
#pragma unroll
            for (int r = 0; r < 4; ++r) {
                const int n = q0 + wave * 32 + g * 16 + quad * 4 + r;
                Y[((size_t)(b * SEQ + n)) * ATT_DIM + h * HD + db * 16 + l15] =
                    (bf16)(o[g][db][r] * linv[r]);
            }
    }
}

// ---------------------------------------------------------------------------
// Kernel 3: out = Y * Woutb^T + b_out (bf16 DMA-staged, BK=64, fp32 out).
// 64x128 tile -> 768 blocks = 3/CU balanced (was 384 = 1.5/CU imbalanced).
// ---------------------------------------------------------------------------
__global__ __launch_bounds__(256) void out_gemm(const bf16* __restrict__ Yb,
                                                const bf16* __restrict__ Wb,
                                                const float* __restrict__ bias,
                                                float* __restrict__ out) {
    __shared__ __align__(16) bf16 As[64 * 64];    // 8 KB
    __shared__ __align__(16) bf16 Bs[128 * 64];   // 16 KB

    const int tid  = threadIdx.x;
    const int bm0  = blockIdx.y * 64;
    const int bn0  = blockIdx.x * 128;
    const int wave = tid >> 6, lane = tid & 63;
    const int quad = lane >> 4, l15 = lane & 15;
    const int wm = (wave >> 1) * 32, wn = (wave & 1) * 64;
    const int r8 = lane >> 3, cc = (lane & 7) ^ r8;

    const bf16* ag = Yb + (size_t)(bm0 + wave * 16 + r8) * ATT_DIM + cc * 8;
    const bf16* bg = Wb + (size_t)(bn0 + wave * 32 + r8) * ATT_DIM + cc * 8;

    floatx4 acc[2][4];
#pragma unroll
    for (int i = 0; i < 2; ++i)
#pragma unroll
        for (int j = 0; j < 4; ++j) acc[i][j] = (floatx4){0.f, 0.f, 0.f, 0.f};

    for (int kt = 0; kt < ATT_DIM / 64; ++kt) {
        __syncthreads();
#pragma unroll
        for (int it = 0; it < 2; ++it)
            cp16(&As[(wave * 16 + it * 8) * 64], ag + it * (8 * ATT_DIM) + kt * 64);
#pragma unroll
        for (int it = 0; it < 4; ++it)
            cp16(&Bs[(wave * 32 + it * 8) * 64], bg + it * (8 * ATT_DIM) + kt * 64);
        __syncthreads();

#pragma unroll
        for (int kh = 0; kh < 2; ++kh) {
            bf16x8 af[2], bfr[4];
#pragma unroll
            for (int i = 0; i < 2; ++i)
                af[i]  = *(const bf16x8*)swz(As, wm + i * 16 + l15, kh * 4 + quad);
#pragma unroll
            for (int j = 0; j < 4; ++j)
                bfr[j] = *(const bf16x8*)swz(Bs, wn + j * 16 + l15, kh * 4 + quad);
#pragma unroll
            for (int i = 0; i < 2; ++i)
#pragma unroll
                for (int j = 0; j < 4; ++j)
                    acc[i][j] = __builtin_amdgcn_mfma_f32_16x16x32_bf16(af[i], bfr[j], acc[i][j], 0, 0, 0);
        }
    }

#pragma unroll
    for (int i = 0; i < 2; ++i)
#pragma unroll
        for (int j = 0; j < 4; ++j)
#pragma unroll
            for (int r = 0; r < 4; ++r) {
                const int row = bm0 + wm + i * 16 + quad * 4 + r;
                const int col = bn0 + wn + j * 16 + l15;
                out[(size_t)row * IN_DIM + col] = acc[i][j][r] + bias[col];
            }
}

// ---------------------------------------------------------------------------
extern "C" void kernel_launch(void* const* d_in, const int* in_sizes, int n_in,
                              void* d_out, int out_size, void* d_ws, size_t ws_size,
                              hipStream_t stream) {
    const float* X    = (const float*)d_in[0];
    const float* Wqkv = (const float*)d_in[1];
    const float* Wout = (const float*)d_in[2];
    const float* bout = (const float*)d_in[3];
    float* out = (float*)d_out;

    char* ws = (char*)d_ws;
    size_t off = 0;
    bf16* Xb  = (bf16*)(ws + off); off += (size_t)M_TOT * IN_DIM * 2;
    bf16* Wqb = (bf16*)(ws + off); off += (size_t)QKV_N * IN_DIM * 2;
    bf16* Wob = (bf16*)(ws + off); off += (size_t)IN_DIM * ATT_DIM * 2;
    const size_t T = (size_t)BATCH * NH * SEQ * HD * 2;
    bf16* Q  = (bf16*)(ws + off); off += T;
    bf16* K  = (bf16*)(ws + off); off += T;
    bf16* VT = (bf16*)(ws + off); off += T;
    bf16* Y  = (bf16*)(ws + off); off += T;

    cvt_all<<<N8_ALL / 256, 256, 0, stream>>>(X, Wqkv, Wout, Xb, Wqb, Wob);
    qkv_gemm<<<dim3(QKV_N / 128, M_TOT / 128), 256, 0, stream>>>(Xb, Wqb, Q, K, VT);
    attn<<<dim3(BATCH * NH, SEQ / 128), 256, 0, stream>>>(Q, K, VT, Y);
    out_gemm<<<dim3(IN_DIM / 128, M_TOT / 64), 256, 0, stream>>>(Y, Wob, bout, out);
}

// Round 7
// 160.118 us; speedup vs baseline: 1.1146x; 1.1146x over previous
//
#include <hip/hip_runtime.h>

typedef __bf16 bf16;
typedef unsigned int u32;
typedef __attribute__((ext_vector_type(8))) __bf16 bf16x8;
typedef __attribute__((ext_vector_type(4))) __bf16 bf16x4;
typedef __attribute__((ext_vector_type(4))) float floatx4;

#define IN_DIM  768
#define ATT_DIM 512
#define NH      8
#define HD      64
#define BATCH   4
#define SEQ     2048
#define M_TOT   (BATCH*SEQ)     // 8192
#define QKV_N   (3*ATT_DIM)     // 1536

// Q scale: 1/sqrt(64) * log2(e)  -> scores exit MFMA in log2 domain
#define QSCALE 0.18033688011112042f

// async 16B global->LDS copy. LDS dest = wave-uniform base + lane*16.
__device__ __forceinline__ void cp16(void* lds, const void* g) {
    __builtin_amdgcn_global_load_lds((const __attribute__((address_space(1))) u32*)g,
                                     (__attribute__((address_space(3))) u32*)lds, 16, 0, 0);
}
// XOR-swizzled accessor for 64-col bf16 tiles staged by cp16:
// 16B chunk c (0..7) of row r lives at slot c ^ (r&7).  (R2-measured: ~free)
__device__ __forceinline__ const bf16* swz(const bf16* b, int row, int chunk) {
    return b + row * 64 + (((chunk) ^ (row & 7)) << 3);
}
// 128-col variant: 16 chunks/row, slot = c ^ (r&15) -> 2-way max on reads.
__device__ __forceinline__ const bf16* swz128(const bf16* b, int row, int chunk) {
    return b + row * 128 + (((chunk) ^ (row & 15)) << 3);
}

// ---------------------------------------------------------------------------
// Kernel 0: fp32 -> bf16 conversion of X, W_qkv, W_out
// ---------------------------------------------------------------------------
#define N8_X  (M_TOT * IN_DIM / 8)
#define N8_WQ (QKV_N * IN_DIM / 8)
#define N8_WO (IN_DIM * ATT_DIM / 8)
#define N8_ALL (N8_X + N8_WQ + N8_WO)

__global__ __launch_bounds__(256) void cvt_all(const float* __restrict__ X,
                                               const float* __restrict__ Wq,
                                               const float* __restrict__ Wo,
                                               bf16* __restrict__ Xb,
                                               bf16* __restrict__ Wqb,
                                               bf16* __restrict__ Wob) {
    int i = blockIdx.x * 256 + threadIdx.x;
    const float* s; bf16* d; int off;
    if (i < N8_X)            { s = X;  d = Xb;  off = i; }
    else if (i < N8_X+N8_WQ) { s = Wq; d = Wqb; off = i - N8_X; }
    else                     { s = Wo; d = Wob; off = i - N8_X - N8_WQ; }
    const float4 a = ((const float4*)s)[2*off];
    const float4 b = ((const float4*)s)[2*off+1];
    bf16x8 o = {(bf16)a.x,(bf16)a.y,(bf16)a.z,(bf16)a.w,
                (bf16)b.x,(bf16)b.y,(bf16)b.z,(bf16)b.w};
    ((bf16x8*)d)[off] = o;
}

// ---------------------------------------------------------------------------
// Kernel 1: QKV = Xb * Wqkvb^T (bf16, DMA-staged, BK=64).
// Q,K -> [b][h][n][d] (Q pre-scaled); V -> transposed [b][h][d][n] via LDS.
// ---------------------------------------------------------------------------
__global__ __launch_bounds__(256) void qkv_gemm(const bf16* __restrict__ Xb,
                                                const bf16* __restrict__ Wb,
                                                bf16* __restrict__ Q,
                                                bf16* __restrict__ Kv,
                                                bf16* __restrict__ VT) {
    __shared__ __align__(16) char smraw[34816];
    bf16* As = (bf16*)smraw;
    bf16* Bs = (bf16*)(smraw + 16384);

    const int tid  = threadIdx.x;
    const int bm0  = blockIdx.y * 128;
    const int bn0  = blockIdx.x * 128;
    const int wave = tid >> 6, lane = tid & 63;
    const int quad = lane >> 4, l15 = lane & 15;
    const int wm = (wave >> 1) * 64, wn = (wave & 1) * 64;
    const int r8 = lane >> 3, cc = (lane & 7) ^ r8;

    const bf16* ag = Xb + (size_t)(bm0 + wave * 32 + r8) * IN_DIM + cc * 8;
    const bf16* bg = Wb + (size_t)(bn0 + wave * 32 + r8) * IN_DIM + cc * 8;

    floatx4 acc[4][4];
#pragma unroll
    for (int i = 0; i < 4; ++i)
#pragma unroll
        for (int j = 0; j < 4; ++j) acc[i][j] = (floatx4){0.f, 0.f, 0.f, 0.f};

    for (int kt = 0; kt < IN_DIM / 64; ++kt) {
        __syncthreads();
#pragma unroll
        for (int it = 0; it < 4; ++it) {
            cp16(&As[(wave * 32 + it * 8) * 64], ag + it * (8 * IN_DIM) + kt * 64);
            cp16(&Bs[(wave * 32 + it * 8) * 64], bg + it * (8 * IN_DIM) + kt * 64);
        }
        __syncthreads();

        bf16x8 af[2][4], bfr[2][4];
#pragma unroll
        for (int kh = 0; kh < 2; ++kh)
#pragma unroll
            for (int i = 0; i < 4; ++i) {
                af[kh][i]  = *(const bf16x8*)swz(As, wm + i * 16 + l15, kh * 4 + quad);
                bfr[kh][i] = *(const bf16x8*)swz(Bs, wn + i * 16 + l15, kh * 4 + quad);
            }
#pragma unroll
        for (int kh = 0; kh < 2; ++kh)
#pragma unroll
            for (int i = 0; i < 4; ++i)
#pragma unroll
                for (int j = 0; j < 4; ++j)
                    acc[i][j] = __builtin_amdgcn_mfma_f32_16x16x32_bf16(af[kh][i], bfr[kh][j], acc[i][j], 0, 0, 0);
    }

    const int b = bm0 >> 11, nbase = bm0 & 2047;

    if (bn0 < 1024) {
#pragma unroll
        for (int i = 0; i < 4; ++i)
#pragma unroll
            for (int j = 0; j < 4; ++j)
#pragma unroll
                for (int r = 0; r < 4; ++r) {
                    const int row = bm0 + wm + i * 16 + quad * 4 + r;
                    const int col = bn0 + wn + j * 16 + l15;
                    const float v = acc[i][j][r];
                    const int rem = col & 511;
                    const int h = rem >> 6, d = rem & 63;
                    const int n = row & 2047;
                    const size_t idx = (((size_t)((row >> 11) * NH + h)) * SEQ + n) * HD + d;
                    if (col < 512) Q[idx]  = (bf16)(v * QSCALE);
                    else           Kv[idx] = (bf16)v;
                }
    } else {
        __syncthreads();
        bf16 (*Ts)[136] = (bf16(*)[136])smraw;
#pragma unroll
        for (int i = 0; i < 4; ++i)
#pragma unroll
            for (int j = 0; j < 4; ++j) {
                bf16x4 pk = {(bf16)acc[i][j][0], (bf16)acc[i][j][1],
                             (bf16)acc[i][j][2], (bf16)acc[i][j][3]};
                *(bf16x4*)&Ts[wn + j * 16 + l15][wm + i * 16 + quad * 4] = pk;
            }
        __syncthreads();
        const int cb = bn0 - 1024;
#pragma unroll
        for (int t2 = 0; t2 < 8; ++t2) {
            const int id = tid + t2 * 256;
            const int c = id >> 4, nc = (id & 15) * 8;
            const int col = cb + c;
            const int h = col >> 6, d = col & 63;
            *(bf16x8*)&VT[(((size_t)(b * NH + h)) * HD + d) * SEQ + nbase + nc] =
                *(const bf16x8*)&Ts[c][nc];
        }
    }
}

// ---------------------------------------------------------------------------
// Kernel 2: flash attention, no-max softmax, S^T scheme, 32 q-rows/wave,
// 128 KEYS PER BARRIER (2 sub-tiles of 64). Block = 128 Q rows, grid
// (32 bh, 16 qt) = 512 blocks, 2/CU (LDS exactly 80 KB). K/V dbuf, ONE
// barrier per 128 keys; the two sub-tile chains overlap each other's
// P round-trip and ds_read latencies.
// ---------------------------------------------------------------------------
__global__ __launch_bounds__(256, 2) void attn(const bf16* __restrict__ Q,
                                               const bf16* __restrict__ K,
                                               const bf16* __restrict__ VT,
                                               bf16* __restrict__ Y) {
    __shared__ bf16 Ks[2][128 * 64];    // 32 KB: 128 keys x 64 d, swz
    __shared__ bf16 VTs[2][64 * 128];   // 32 KB: 64 d x 128 keys, swz128
    __shared__ bf16 Ps[4][2][16 * 64];  // 16 KB: per-wave per-group strip

    const int tid  = threadIdx.x;
    const int wave = tid >> 6, lane = tid & 63;
    const int quad = lane >> 4, l15 = lane & 15;
    const int bh = blockIdx.x;                 // bh fast dim: same-XCD L2 reuse
    const int q0 = blockIdx.y * 128;
    const bf16* Qg = Q  + (size_t)bh * SEQ * HD;
    const bf16* Kg = K  + (size_t)bh * SEQ * HD;
    const bf16* Vg = VT + (size_t)bh * HD * SEQ;

    // K staging lanes: 8 rows x 8 chunks, swz (row&7)
    const int r8 = lane >> 3, cc = (lane & 7) ^ r8;
    // V staging lanes: 4 rows x 16 chunks, swz128. Row base per it is a
    // multiple of 4; swizzle uses (row&15) = it*4 + (lane>>4).
    const int r4 = lane >> 4;

    // Q fragments straight from global (once): 2 groups x 16 rows
    bf16x8 aq[2][2];
#pragma unroll
    for (int g = 0; g < 2; ++g) {
        const size_t qrow = (size_t)(q0 + wave * 32 + g * 16 + l15) * 64;
        aq[g][0] = *(const bf16x8*)&Qg[qrow + quad * 8];
        aq[g][1] = *(const bf16x8*)&Qg[qrow + 32 + quad * 8];
    }

    // staging source pointers (per wave): K rows wave*32 + it*8 + r8
    const bf16* kgw = Kg + (size_t)(wave * 32 + r8) * 64 + cc * 8;
    // V rows (d) = wave*16 + it*4 + r4, chunk = (lane&15) ^ (row&15)
    float l[2] = {0.f, 0.f};
    floatx4 o[2][4];
#pragma unroll
    for (int g = 0; g < 2; ++g)
#pragma unroll
        for (int db = 0; db < 4; ++db) o[g][db] = (floatx4){0.f, 0.f, 0.f, 0.f};

    // prologue: stage tile 0 (128 keys)
#pragma unroll
    for (int it = 0; it < 4; ++it)
        cp16(&Ks[0][(wave * 32 + it * 8) * 64], kgw + (size_t)it * 8 * 64);
#pragma unroll
    for (int it = 0; it < 4; ++it) {
        const int vrow = wave * 16 + it * 4 + r4;
        const int vcc = (lane & 15) ^ (vrow & 15);
        cp16(&VTs[0][(wave * 16 + it * 4) * 128],
             Vg + (size_t)vrow * 2048 + vcc * 8);
    }

    for (int kt = 0; kt < SEQ / 128; ++kt) {
        const int cur = kt & 1, nb = cur ^ 1;
        __syncthreads();   // drains DMA(kt) (issued one full iter ago)
        if (kt < SEQ / 128 - 1) {
#pragma unroll
            for (int it = 0; it < 4; ++it)
                cp16(&Ks[nb][(wave * 32 + it * 8) * 64],
                     kgw + (size_t)(kt + 1) * 128 * 64 + (size_t)it * 8 * 64);
#pragma unroll
            for (int it = 0; it < 4; ++it) {
                const int vrow = wave * 16 + it * 4 + r4;
                const int vcc = (lane & 15) ^ (vrow & 15);
                cp16(&VTs[nb][(wave * 16 + it * 4) * 128],
                     Vg + (size_t)vrow * 2048 + (kt + 1) * 128 + vcc * 8);
            }
        }

#pragma unroll
        for (int s = 0; s < 2; ++s) {
            // S^T phase, sub-tile s (keys s*64..s*64+63)
#pragma unroll
            for (int t = 0; t < 4; ++t) {
                const int kr = s * 64 + t * 16 + l15;
                const bf16x8 k0 = *(const bf16x8*)swz(Ks[cur], kr, quad);
                const bf16x8 k1 = *(const bf16x8*)swz(Ks[cur], kr, 4 + quad);
                const int c = t * 2 + (quad >> 1);
                const int poff = l15 * 64 + ((c ^ (l15 & 7)) << 3) + ((quad & 1) << 2);
#pragma unroll
                for (int g = 0; g < 2; ++g) {
                    floatx4 z = (floatx4){0.f, 0.f, 0.f, 0.f};
                    z = __builtin_amdgcn_mfma_f32_16x16x32_bf16(k0, aq[g][0], z, 0, 0, 0);
                    z = __builtin_amdgcn_mfma_f32_16x16x32_bf16(k1, aq[g][1], z, 0, 0, 0);
                    const float p0 = __builtin_amdgcn_exp2f(z[0]);
                    const float p1 = __builtin_amdgcn_exp2f(z[1]);
                    const float p2 = __builtin_amdgcn_exp2f(z[2]);
                    const float p3 = __builtin_amdgcn_exp2f(z[3]);
                    l[g] += (p0 + p1) + (p2 + p3);
                    bf16x4 pk = {(bf16)p0, (bf16)p1, (bf16)p2, (bf16)p3};
                    *(bf16x4*)&Ps[wave][g][poff] = pk;
                }
            }
            // P A-fragments
            bf16x8 pa[2][2];
#pragma unroll
            for (int g = 0; g < 2; ++g) {
                pa[g][0] = *(const bf16x8*)swz(&Ps[wave][g][0], l15, quad);
                pa[g][1] = *(const bf16x8*)swz(&Ps[wave][g][0], l15, 4 + quad);
            }
            // O += P*V, sub-tile s; V frags shared across groups
#pragma unroll
            for (int db = 0; db < 4; ++db) {
                const int vr = db * 16 + l15;
                const bf16x8 v0 = *(const bf16x8*)swz128(VTs[cur], vr, s * 8 + quad);
                const bf16x8 v1 = *(const bf16x8*)swz128(VTs[cur], vr, s * 8 + 4 + quad);
#pragma unroll
                for (int g = 0; g < 2; ++g) {
                    o[g][db] = __builtin_amdgcn_mfma_f32_16x16x32_bf16(pa[g][0], v0, o[g][db], 0, 0, 0);
                    o[g][db] = __builtin_amdgcn_mfma_f32_16x16x32_bf16(pa[g][1], v1, o[g][db], 0, 0, 0);
                }
            }
        }
    }

    // final row-sum reduction + distribute 1/l to C-layout rows, write
    const int b = bh >> 3, h = bh & 7;
#pragma unroll
    for (int g = 0; g < 2; ++g) {
        float lg = l[g];
        lg += __shfl_xor(lg, 16, 64);
        lg += __shfl_xor(lg, 32, 64);
        const float inv = 1.0f / lg;
        float linv[4];
#pragma unroll
        for (int r = 0; r < 4; ++r)
            linv[r] = __int_as_float(__builtin_amdgcn_ds_bpermute((quad * 4 + r) * 4,
                                                                  __float_as_int(inv)));
#pragma unroll
        for (int db = 0; db < 4; ++db)
#pragma unroll
            for (int r = 0; r < 4; ++r) {
                const int n = q0 + wave * 32 + g * 16 + quad * 4 + r;
                Y[((size_t)(b * SEQ + n)) * ATT_DIM + h * HD + db * 16 + l15] =
                    (bf16)(o[g][db][r] * linv[r]);
            }
    }
}

// ---------------------------------------------------------------------------
// Kernel 3: out = Y * Woutb^T + b_out (bf16 DMA-staged, BK=64, fp32 out).
// 128x128 tile (R5 config — R6's 64x128 regressed ~4 us).
// ---------------------------------------------------------------------------
__global__ __launch_bounds__(256) void out_gemm(const bf16* __restrict__ Yb,
                                                const bf16* __restrict__ Wb,
                                                const float* __restrict__ bias,
                                                float* __restrict__ out) {
    __shared__ __align__(16) bf16 As[128 * 64];
    __shared__ __align__(16) bf16 Bs[128 * 64];

    const int tid  = threadIdx.x;
    const int bm0  = blockIdx.y * 128;
    const int bn0  = blockIdx.x * 128;
    const int wave = tid >> 6, lane = tid & 63;
    const int quad = lane >> 4, l15 = lane & 15;
    const int wm = (wave >> 1) * 64, wn = (wave & 1) * 64;
    const int r8 = lane >> 3, cc = (lane & 7) ^ r8;

    const bf16* ag = Yb + (size_t)(bm0 + wave * 32 + r8) * ATT_DIM + cc * 8;
    const bf16* bg = Wb + (size_t)(bn0 + wave * 32 + r8) * ATT_DIM + cc * 8;

    floatx4 acc[4][4];
#pragma unroll
    for (int i = 0; i < 4; ++i)
#pragma unroll
        for (int j = 0; j < 4; ++j) acc[i][j] = (floatx4){0.f, 0.f, 0.f, 0.f};

    for (int kt = 0; kt < ATT_DIM / 64; ++kt) {
        __syncthreads();
#pragma unroll
        for (int it = 0; it < 4; ++it) {
            cp16(&As[(wave * 32 + it * 8) * 64], ag + it * (8 * ATT_DIM) + kt * 64);
            cp16(&Bs[(wave * 32 + it * 8) * 64], bg + it * (8 * ATT_DIM) + kt * 64);
        }
        __syncthreads();

        bf16x8 af[2][4], bfr[2][4];
#pragma unroll
        for (int kh = 0; kh < 2; ++kh)
#pragma unroll
            for (int i = 0; i < 4; ++i) {
                af[kh][i]  = *(const bf16x8*)swz(As, wm + i * 16 + l15, kh * 4 + quad);
                bfr[kh][i] = *(const bf16x8*)swz(Bs, wn + i * 16 + l15, kh * 4 + quad);
            }
#pragma unroll
        for (int kh = 0; kh < 2; ++kh)
#pragma unroll
            for (int i = 0; i < 4; ++i)
#pragma unroll
                for (int j = 0; j < 4; ++j)
                    acc[i][j] = __builtin_amdgcn_mfma_f32_16x16x32_bf16(af[kh][i], bfr[kh][j], acc[i][j], 0, 0, 0);
    }

#pragma unroll
    for (int i = 0; i < 4; ++i)
#pragma unroll
        for (int j = 0; j < 4; ++j)
#pragma unroll
            for (int r = 0; r < 4; ++r) {
                const int row = bm0 + wm + i * 16 + quad * 4 + r;
                const int col = bn0 + wn + j * 16 + l15;
                out[(size_t)row * IN_DIM + col] = acc[i][j][r] + bias[col];
            }
}

// ---------------------------------------------------------------------------
extern "C" void kernel_launch(void* const* d_in, const int* in_sizes, int n_in,
                              void* d_out, int out_size, void* d_ws, size_t ws_size,
                              hipStream_t stream) {
    const float* X    = (const float*)d_in[0];
    const float* Wqkv = (const float*)d_in[1];
    const float* Wout = (const float*)d_in[2];
    const float* bout = (const float*)d_in[3];
    float* out = (float*)d_out;

    char* ws = (char*)d_ws;
    size_t off = 0;
    bf16* Xb  = (bf16*)(ws + off); off += (size_t)M_TOT * IN_DIM * 2;
    bf16* Wqb = (bf16*)(ws + off); off += (size_t)QKV_N * IN_DIM * 2;
    bf16* Wob = (bf16*)(ws + off); off += (size_t)IN_DIM * ATT_DIM * 2;
    const size_t T = (size_t)BATCH * NH * SEQ * HD * 2;
    bf16* Q  = (bf16*)(ws + off); off += T;
    bf16* K  = (bf16*)(ws + off); off += T;
    bf16* VT = (bf16*)(ws + off); off += T;
    bf16* Y  = (bf16*)(ws + off); off += T;

    cvt_all<<<N8_ALL / 256, 256, 0, stream>>>(X, Wqkv, Wout, Xb, Wqb, Wob);
    qkv_gemm<<<dim3(QKV_N / 128, M_TOT / 128), 256, 0, stream>>>(Xb, Wqb, Q, K, VT);
    attn<<<dim3(BATCH * NH, SEQ / 128), 256, 0, stream>>>(Q, K, VT, Y);
    out_gemm<<<dim3(IN_DIM / 128, M_TOT / 128), 256, 0, stream>>>(Y, Wob, bout, out);
}